// Round 3
// baseline (334.095 us; speedup 1.0000x reference)
//
#include <hip/hip_runtime.h>
#include <stdint.h>

#define NUM_EXPERT 8
#define IN_FEAT 1024
#define OUT_FEAT 4096
#define N_TOKENS 4096

#define BM 128
#define BN 128
#define BK 32                 // fp32 tiles: 128 x 32 x 4B = 16 KB each
#define MAX_ROW_TILES 40      // worst-case sum_e ceil(cnt_e/128) = 39

typedef __attribute__((ext_vector_type(8))) short short8;   // 8 x bf16 bits
typedef __attribute__((ext_vector_type(4))) float f32x4;

__device__ __forceinline__ void async_cp16(const void* g, void* l) {
    __builtin_amdgcn_global_load_lds(
        (const __attribute__((address_space(1))) void*)g,
        (__attribute__((address_space(3))) void*)l, 16, 0, 0);
}

// pack 8 fp32 -> 8 bf16 (truncation) with 4 x v_perm_b32
__device__ __forceinline__ short8 pack8_bf16(f32x4 lo, f32x4 hi) {
    union { short8 s; unsigned int u[4]; } r;
    r.u[0] = __builtin_amdgcn_perm(__float_as_uint(lo.y), __float_as_uint(lo.x), 0x07060302u);
    r.u[1] = __builtin_amdgcn_perm(__float_as_uint(lo.w), __float_as_uint(lo.z), 0x07060302u);
    r.u[2] = __builtin_amdgcn_perm(__float_as_uint(hi.y), __float_as_uint(hi.x), 0x07060302u);
    r.u[3] = __builtin_amdgcn_perm(__float_as_uint(hi.w), __float_as_uint(hi.z), 0x07060302u);
    return r.s;
}

// Fused MoE grouped GEMM, fp32 I/O, bf16 MFMA compute.
// C[tok][n] = sum_k inp[tok][k] * W[e][n][k]   (both operands K-contiguous)
__global__ __launch_bounds__(256)
void moe_gemm(const float* __restrict__ inp,
              const float* __restrict__ weight,
              const int* __restrict__ gate,
              float* __restrict__ out) {
    __shared__ int cnt[NUM_EXPERT];
    __shared__ int wsum[4];
    __shared__ int toks[BM];
    __shared__ __align__(16) float As[BM * BK];   // 16 KB
    __shared__ __align__(16) float Bs[BN * BK];   // 16 KB

    const int tid  = threadIdx.x;
    const int lane = tid & 63;
    const int wave = tid >> 6;

    // ---- Phase A: each thread loads 16 gates, counts per expert ----
    int gv[16];
    const int4* gp = (const int4*)(gate + tid * 16);
#pragma unroll
    for (int i = 0; i < 4; ++i) {
        int4 v = gp[i];
        gv[i * 4 + 0] = v.x; gv[i * 4 + 1] = v.y;
        gv[i * 4 + 2] = v.z; gv[i * 4 + 3] = v.w;
    }
    int lc[NUM_EXPERT];
#pragma unroll
    for (int e2 = 0; e2 < NUM_EXPERT; ++e2) {
        int c = 0;
#pragma unroll
        for (int j = 0; j < 16; ++j) c += (gv[j] == e2) ? 1 : 0;
        lc[e2] = c;
    }
    if (tid < NUM_EXPERT) cnt[tid] = 0;
    if (tid < BM) toks[tid] = 0;      // tail rows -> token 0 (in-bounds; stores masked)
    __syncthreads();
#pragma unroll
    for (int e2 = 0; e2 < NUM_EXPERT; ++e2) {
        int c = lc[e2];
#pragma unroll
        for (int d = 32; d > 0; d >>= 1) c += __shfl_down(c, d);
        if (lane == 0 && c) atomicAdd(&cnt[e2], c);
    }
    __syncthreads();

    // ---- map blockIdx.y -> (expert, local row-tile); block-uniform ----
    int local = blockIdx.y;
    int e = -1, grp_cnt = 0;
#pragma unroll
    for (int i = 0; i < NUM_EXPERT; ++i) {
        int c = cnt[i];
        int t = (c + BM - 1) >> 7;
        if (e < 0) {
            if (local < t) { e = i; grp_cnt = c; }
            else           local -= t;
        }
    }
    if (e < 0) return;

    const int n0   = blockIdx.x * BN;
    const int row0 = local * BM;
    int vcnt = grp_cnt - row0; if (vcnt > BM) vcnt = BM;

    // ---- Phase B: prefix scan -> within-expert ranks -> token list ----
    int c_t = 0;
#pragma unroll
    for (int e2 = 0; e2 < NUM_EXPERT; ++e2) if (e2 == e) c_t = lc[e2];
    int inc = c_t;
#pragma unroll
    for (int d = 1; d < 64; d <<= 1) {
        int t = __shfl_up(inc, d);
        if (lane >= d) inc += t;
    }
    if (lane == 63) wsum[wave] = inc;
    __syncthreads();
    int base = 0;
#pragma unroll
    for (int w = 0; w < 4; ++w) if (w < wave) base += wsum[w];
    int rank = base + inc - c_t;
#pragma unroll
    for (int j = 0; j < 16; ++j) {
        if (gv[j] == e) {
            int rr = rank - row0;
            if (rr >= 0 && rr < BM) toks[rr] = tid * 16 + j;
            rank++;
        }
    }
    __syncthreads();

    // ---- staging: 2048 x 16B chunks per iter (1024 A + 1024 B), 8/thread.
    // fp32 row of BK=32 floats = 128 B = 8 chunks; LDS slot (row=c>>3, kcp=c&7)
    // receives global chunk kc = kcp ^ (row&7) (XOR swizzle).
    const char* ag[4]; const char* bg[4];
    char* al[4]; char* bl[4];
    const char* inp_b = (const char*)inp;
    const char* w_b   = (const char*)weight + (size_t)e * (size_t)(OUT_FEAT * IN_FEAT) * 4;
#pragma unroll
    for (int i = 0; i < 4; ++i) {
        int c   = i * 256 + tid;
        int row = c >> 3;
        int kc  = (c & 7) ^ (row & 7);
        ag[i] = inp_b + (size_t)toks[row] * (IN_FEAT * 4) + kc * 16;
        bg[i] = w_b   + (size_t)(n0 + row) * (IN_FEAT * 4) + kc * 16;
        al[i] = (char*)As + c * 16;
        bl[i] = (char*)Bs + c * 16;
    }

    // ---- fragment LDS byte offsets: row*128 + ((2*quad+i)^(row&7))*16 ----
    const int wm   = (wave & 1) * 64;
    const int wn   = (wave >> 1) * 64;
    const int lcol = lane & 15;
    const int quad = lane >> 4;

    int aoff[4][2], boff[4][2];
#pragma unroll
    for (int t = 0; t < 4; ++t)
#pragma unroll
        for (int i = 0; i < 2; ++i) {
            int ra = wm + t * 16 + lcol;
            aoff[t][i] = ra * 128 + (((2 * quad + i) ^ (ra & 7)) * 16);
            int rb = wn + t * 16 + lcol;
            boff[t][i] = rb * 128 + (((2 * quad + i) ^ (rb & 7)) * 16);
        }

    const f32x4 vzero = {0.f, 0.f, 0.f, 0.f};
    f32x4 acc[4][4];
#pragma unroll
    for (int i = 0; i < 4; ++i)
#pragma unroll
        for (int j = 0; j < 4; ++j) acc[i][j] = vzero;

    const char* As_b = (const char*)As;
    const char* Bs_b = (const char*)Bs;

    for (int k0 = 0; k0 < IN_FEAT; k0 += BK) {
#pragma unroll
        for (int i = 0; i < 4; ++i) { async_cp16(ag[i], al[i]); ag[i] += BK * 4; }
#pragma unroll
        for (int i = 0; i < 4; ++i) { async_cp16(bg[i], bl[i]); bg[i] += BK * 4; }
        __builtin_amdgcn_s_waitcnt(0);   // drain global_load_lds before barrier
        __syncthreads();

        short8 af[4], bf[4];
#pragma unroll
        for (int im = 0; im < 4; ++im) {
            f32x4 x0 = *(const f32x4*)(As_b + aoff[im][0]);
            f32x4 x1 = *(const f32x4*)(As_b + aoff[im][1]);
            af[im] = pack8_bf16(x0, x1);
        }
#pragma unroll
        for (int jn = 0; jn < 4; ++jn) {
            f32x4 x0 = *(const f32x4*)(Bs_b + boff[jn][0]);
            f32x4 x1 = *(const f32x4*)(Bs_b + boff[jn][1]);
            bf[jn] = pack8_bf16(x0, x1);
        }
#pragma unroll
        for (int im = 0; im < 4; ++im)
#pragma unroll
            for (int jn = 0; jn < 4; ++jn)
                acc[im][jn] = __builtin_amdgcn_mfma_f32_16x16x32_bf16(
                    af[im], bf[jn], acc[im][jn], 0, 0, 0);
        __syncthreads();
    }

    // ---- epilogue: C/D layout col=lane&15, row=quad*4+reg; fp32 scatter ----
#pragma unroll
    for (int im = 0; im < 4; ++im) {
#pragma unroll
        for (int reg = 0; reg < 4; ++reg) {
            int r = wm + im * 16 + quad * 4 + reg;
            if (r < vcnt) {
                float* orow = out + (size_t)toks[r] * OUT_FEAT + (n0 + wn + lcol);
#pragma unroll
                for (int jn = 0; jn < 4; ++jn)
                    orow[jn * 16] = acc[im][jn][reg];
            }
        }
    }
}

extern "C" void kernel_launch(void* const* d_in, const int* in_sizes, int n_in,
                              void* d_out, int out_size, void* d_ws, size_t ws_size,
                              hipStream_t stream) {
    const float* inp    = (const float*)d_in[0];   // fp32 [4096,1024]
    const int*   gate   = (const int*)d_in[1];     // int32 [4096]
    const float* weight = (const float*)d_in[2];   // fp32 [8,4096,1024]
    float*       out    = (float*)d_out;           // fp32 [4096,4096]
    (void)d_ws; (void)ws_size; (void)in_sizes; (void)n_in; (void)out_size;

    dim3 grid(OUT_FEAT / BN, MAX_ROW_TILES);
    moe_gemm<<<grid, 256, 0, stream>>>(inp, weight, gate, out);
}

// Round 4
// 282.673 us; speedup vs baseline: 1.1819x; 1.1819x over previous
//
#include <hip/hip_runtime.h>
#include <stdint.h>

#define NUM_EXPERT 8
#define IN_FEAT 1024
#define OUT_FEAT 4096
#define N_TOKENS 4096

#define BM 128
#define BN 128
#define MAX_ROW_TILES 40      // worst-case sum_e ceil(cnt_e/128) = 39

typedef __attribute__((ext_vector_type(8))) short short8;   // 8 x bf16 bits
typedef __attribute__((ext_vector_type(4))) float f32x4;

__device__ __forceinline__ void async_cp16(const void* g, void* l) {
    __builtin_amdgcn_global_load_lds(
        (const __attribute__((address_space(1))) void*)g,
        (__attribute__((address_space(3))) void*)l, 16, 0, 0);
}

__device__ __forceinline__ unsigned int rne2(float a, float b) {
    // pack 2 fp32 -> 2 bf16 (RNE) into one dword (a=low, b=high)
    unsigned int ua = __float_as_uint(a); ua += 0x7fffu + ((ua >> 16) & 1u);
    unsigned int ub = __float_as_uint(b); ub += 0x7fffu + ((ub >> 16) & 1u);
    return (ua >> 16) | (ub & 0xffff0000u);
}

// ---------------- Kernel 0: fp32 -> bf16 convert (memory-bound) ----------------
__global__ __launch_bounds__(256)
void cvt_bf16(const float4* __restrict__ src, uint2* __restrict__ dst, int n4) {
    int i = blockIdx.x * 256 + threadIdx.x;
    int stride = gridDim.x * 256;
    for (; i < n4; i += stride) {
        float4 v = src[i];
        uint2 r;
        r.x = rne2(v.x, v.y);
        r.y = rne2(v.z, v.w);
        dst[i] = r;
    }
}

// ---------------- Kernel 1: bf16 grouped GEMM (m97 structure) ----------------
// C[tok][n] = sum_k inp[tok][k] * W[e][n][k]   (both operands K-contiguous)
#define BK 64
__global__ __launch_bounds__(256)
void moe_gemm_bf16(const unsigned short* __restrict__ inp,
                   const unsigned short* __restrict__ weight,
                   const int* __restrict__ gate,
                   float* __restrict__ out) {
    __shared__ int cnt[NUM_EXPERT];
    __shared__ int wsum[4];
    __shared__ int toks[BM];
    __shared__ __align__(16) unsigned short As[BM * BK];   // 16 KB
    __shared__ __align__(16) unsigned short Bs[BN * BK];   // 16 KB

    const int tid  = threadIdx.x;
    const int lane = tid & 63;
    const int wave = tid >> 6;

    // ---- Phase A: each thread loads 16 gates, counts per expert ----
    int gv[16];
    const int4* gp = (const int4*)(gate + tid * 16);
#pragma unroll
    for (int i = 0; i < 4; ++i) {
        int4 v = gp[i];
        gv[i * 4 + 0] = v.x; gv[i * 4 + 1] = v.y;
        gv[i * 4 + 2] = v.z; gv[i * 4 + 3] = v.w;
    }
    int lc[NUM_EXPERT];
#pragma unroll
    for (int e2 = 0; e2 < NUM_EXPERT; ++e2) {
        int c = 0;
#pragma unroll
        for (int j = 0; j < 16; ++j) c += (gv[j] == e2) ? 1 : 0;
        lc[e2] = c;
    }
    if (tid < NUM_EXPERT) cnt[tid] = 0;
    if (tid < BM) toks[tid] = 0;      // tail rows -> token 0 (stores masked)
    __syncthreads();
#pragma unroll
    for (int e2 = 0; e2 < NUM_EXPERT; ++e2) {
        int c = lc[e2];
#pragma unroll
        for (int d = 32; d > 0; d >>= 1) c += __shfl_down(c, d);
        if (lane == 0 && c) atomicAdd(&cnt[e2], c);
    }
    __syncthreads();

    // ---- map blockIdx.y -> (expert, local row-tile); block-uniform ----
    int local = blockIdx.y;
    int e = -1, grp_cnt = 0;
#pragma unroll
    for (int i = 0; i < NUM_EXPERT; ++i) {
        int c = cnt[i];
        int t = (c + BM - 1) >> 7;
        if (e < 0) {
            if (local < t) { e = i; grp_cnt = c; }
            else           local -= t;
        }
    }
    if (e < 0) return;

    const int n0   = blockIdx.x * BN;
    const int row0 = local * BM;
    int vcnt = grp_cnt - row0; if (vcnt > BM) vcnt = BM;

    // ---- Phase B: prefix scan -> within-expert ranks -> token list ----
    int c_t = 0;
#pragma unroll
    for (int e2 = 0; e2 < NUM_EXPERT; ++e2) if (e2 == e) c_t = lc[e2];
    int inc = c_t;
#pragma unroll
    for (int d = 1; d < 64; d <<= 1) {
        int t = __shfl_up(inc, d);
        if (lane >= d) inc += t;
    }
    if (lane == 63) wsum[wave] = inc;
    __syncthreads();
    int base = 0;
#pragma unroll
    for (int w = 0; w < 4; ++w) if (w < wave) base += wsum[w];
    int rank = base + inc - c_t;
#pragma unroll
    for (int j = 0; j < 16; ++j) {
        if (gv[j] == e) {
            int rr = rank - row0;
            if (rr >= 0 && rr < BM) toks[rr] = tid * 16 + j;
            rank++;
        }
    }
    __syncthreads();

    // ---- staging: bf16 row of BK=64 = 128 B = 8 chunks of 16 B.
    // LDS slot (row=c>>3, kcp=c&7) receives global chunk kc = kcp ^ (row&7).
    const char* ag[4]; const char* bg[4];
    char* al[4]; char* bl[4];
    const char* inp_b = (const char*)inp;
    const char* w_b   = (const char*)weight + (size_t)e * (size_t)(OUT_FEAT * IN_FEAT) * 2;
#pragma unroll
    for (int i = 0; i < 4; ++i) {
        int c   = i * 256 + tid;
        int row = c >> 3;
        int kc  = (c & 7) ^ (row & 7);
        ag[i] = inp_b + (size_t)toks[row] * (IN_FEAT * 2) + kc * 16;
        bg[i] = w_b   + (size_t)(n0 + row) * (IN_FEAT * 2) + kc * 16;
        al[i] = (char*)As + c * 16;
        bl[i] = (char*)Bs + c * 16;
    }

    // ---- fragment LDS byte offsets: row*128 + ((ks*4+quad)^(row&7))*16 ----
    const int wm   = (wave & 1) * 64;
    const int wn   = (wave >> 1) * 64;
    const int lcol = lane & 15;
    const int quad = lane >> 4;

    int aoff[2][4], boff[2][4];
#pragma unroll
    for (int ks = 0; ks < 2; ++ks)
#pragma unroll
        for (int t = 0; t < 4; ++t) {
            int ra = wm + t * 16 + lcol;
            aoff[ks][t] = ra * 128 + (((ks * 4 + quad) ^ (ra & 7)) * 16);
            int rb = wn + t * 16 + lcol;
            boff[ks][t] = rb * 128 + (((ks * 4 + quad) ^ (rb & 7)) * 16);
        }

    const f32x4 vzero = {0.f, 0.f, 0.f, 0.f};
    f32x4 acc[4][4];
#pragma unroll
    for (int i = 0; i < 4; ++i)
#pragma unroll
        for (int j = 0; j < 4; ++j) acc[i][j] = vzero;

    const char* As_b = (const char*)As;
    const char* Bs_b = (const char*)Bs;

    for (int k0 = 0; k0 < IN_FEAT; k0 += BK) {
#pragma unroll
        for (int i = 0; i < 4; ++i) { async_cp16(ag[i], al[i]); ag[i] += BK * 2; }
#pragma unroll
        for (int i = 0; i < 4; ++i) { async_cp16(bg[i], bl[i]); bg[i] += BK * 2; }
        __builtin_amdgcn_s_waitcnt(0);   // drain global_load_lds before barrier
        __syncthreads();
#pragma unroll
        for (int ks = 0; ks < 2; ++ks) {
            short8 af[4], bf[4];
#pragma unroll
            for (int im = 0; im < 4; ++im) af[im] = *(const short8*)(As_b + aoff[ks][im]);
#pragma unroll
            for (int jn = 0; jn < 4; ++jn) bf[jn] = *(const short8*)(Bs_b + boff[ks][jn]);
#pragma unroll
            for (int im = 0; im < 4; ++im)
#pragma unroll
                for (int jn = 0; jn < 4; ++jn)
                    acc[im][jn] = __builtin_amdgcn_mfma_f32_16x16x32_bf16(
                        af[im], bf[jn], acc[im][jn], 0, 0, 0);
        }
        __syncthreads();
    }

    // ---- epilogue: C/D layout col=lane&15, row=quad*4+reg; fp32 scatter ----
#pragma unroll
    for (int im = 0; im < 4; ++im) {
#pragma unroll
        for (int reg = 0; reg < 4; ++reg) {
            int r = wm + im * 16 + quad * 4 + reg;
            if (r < vcnt) {
                float* orow = out + (size_t)toks[r] * OUT_FEAT + (n0 + wn + lcol);
#pragma unroll
                for (int jn = 0; jn < 4; ++jn)
                    orow[jn * 16] = acc[im][jn][reg];
            }
        }
    }
}
#undef BK

// ---------------- Fallback: fp32-staging kernel (validated in R3) ------------
#define BKF 32
typedef __attribute__((ext_vector_type(8))) short short8f;

__device__ __forceinline__ short8 pack8_bf16(f32x4 lo, f32x4 hi) {
    union { short8 s; unsigned int u[4]; } r;
    r.u[0] = __builtin_amdgcn_perm(__float_as_uint(lo.y), __float_as_uint(lo.x), 0x07060302u);
    r.u[1] = __builtin_amdgcn_perm(__float_as_uint(lo.w), __float_as_uint(lo.z), 0x07060302u);
    r.u[2] = __builtin_amdgcn_perm(__float_as_uint(hi.y), __float_as_uint(hi.x), 0x07060302u);
    r.u[3] = __builtin_amdgcn_perm(__float_as_uint(hi.w), __float_as_uint(hi.z), 0x07060302u);
    return r.s;
}

__global__ __launch_bounds__(256)
void moe_gemm_f32(const float* __restrict__ inp,
                  const float* __restrict__ weight,
                  const int* __restrict__ gate,
                  float* __restrict__ out) {
    __shared__ int cnt[NUM_EXPERT];
    __shared__ int wsum[4];
    __shared__ int toks[BM];
    __shared__ __align__(16) float As[BM * BKF];
    __shared__ __align__(16) float Bs[BN * BKF];

    const int tid  = threadIdx.x;
    const int lane = tid & 63;
    const int wave = tid >> 6;

    int gv[16];
    const int4* gp = (const int4*)(gate + tid * 16);
#pragma unroll
    for (int i = 0; i < 4; ++i) {
        int4 v = gp[i];
        gv[i * 4 + 0] = v.x; gv[i * 4 + 1] = v.y;
        gv[i * 4 + 2] = v.z; gv[i * 4 + 3] = v.w;
    }
    int lc[NUM_EXPERT];
#pragma unroll
    for (int e2 = 0; e2 < NUM_EXPERT; ++e2) {
        int c = 0;
#pragma unroll
        for (int j = 0; j < 16; ++j) c += (gv[j] == e2) ? 1 : 0;
        lc[e2] = c;
    }
    if (tid < NUM_EXPERT) cnt[tid] = 0;
    if (tid < BM) toks[tid] = 0;
    __syncthreads();
#pragma unroll
    for (int e2 = 0; e2 < NUM_EXPERT; ++e2) {
        int c = lc[e2];
#pragma unroll
        for (int d = 32; d > 0; d >>= 1) c += __shfl_down(c, d);
        if (lane == 0 && c) atomicAdd(&cnt[e2], c);
    }
    __syncthreads();

    int local = blockIdx.y;
    int e = -1, grp_cnt = 0;
#pragma unroll
    for (int i = 0; i < NUM_EXPERT; ++i) {
        int c = cnt[i];
        int t = (c + BM - 1) >> 7;
        if (e < 0) {
            if (local < t) { e = i; grp_cnt = c; }
            else           local -= t;
        }
    }
    if (e < 0) return;

    const int n0   = blockIdx.x * BN;
    const int row0 = local * BM;
    int vcnt = grp_cnt - row0; if (vcnt > BM) vcnt = BM;

    int c_t = 0;
#pragma unroll
    for (int e2 = 0; e2 < NUM_EXPERT; ++e2) if (e2 == e) c_t = lc[e2];
    int inc = c_t;
#pragma unroll
    for (int d = 1; d < 64; d <<= 1) {
        int t = __shfl_up(inc, d);
        if (lane >= d) inc += t;
    }
    if (lane == 63) wsum[wave] = inc;
    __syncthreads();
    int base = 0;
#pragma unroll
    for (int w = 0; w < 4; ++w) if (w < wave) base += wsum[w];
    int rank = base + inc - c_t;
#pragma unroll
    for (int j = 0; j < 16; ++j) {
        if (gv[j] == e) {
            int rr = rank - row0;
            if (rr >= 0 && rr < BM) toks[rr] = tid * 16 + j;
            rank++;
        }
    }
    __syncthreads();

    const char* ag[4]; const char* bg[4];
    char* al[4]; char* bl[4];
    const char* inp_b = (const char*)inp;
    const char* w_b   = (const char*)weight + (size_t)e * (size_t)(OUT_FEAT * IN_FEAT) * 4;
#pragma unroll
    for (int i = 0; i < 4; ++i) {
        int c   = i * 256 + tid;
        int row = c >> 3;
        int kc  = (c & 7) ^ (row & 7);
        ag[i] = inp_b + (size_t)toks[row] * (IN_FEAT * 4) + kc * 16;
        bg[i] = w_b   + (size_t)(n0 + row) * (IN_FEAT * 4) + kc * 16;
        al[i] = (char*)As + c * 16;
        bl[i] = (char*)Bs + c * 16;
    }

    const int wm   = (wave & 1) * 64;
    const int wn   = (wave >> 1) * 64;
    const int lcol = lane & 15;
    const int quad = lane >> 4;

    int aoff[4][2], boff[4][2];
#pragma unroll
    for (int t = 0; t < 4; ++t)
#pragma unroll
        for (int i = 0; i < 2; ++i) {
            int ra = wm + t * 16 + lcol;
            aoff[t][i] = ra * 128 + (((2 * quad + i) ^ (ra & 7)) * 16);
            int rb = wn + t * 16 + lcol;
            boff[t][i] = rb * 128 + (((2 * quad + i) ^ (rb & 7)) * 16);
        }

    const f32x4 vzero = {0.f, 0.f, 0.f, 0.f};
    f32x4 acc[4][4];
#pragma unroll
    for (int i = 0; i < 4; ++i)
#pragma unroll
        for (int j = 0; j < 4; ++j) acc[i][j] = vzero;

    const char* As_b = (const char*)As;
    const char* Bs_b = (const char*)Bs;

    for (int k0 = 0; k0 < IN_FEAT; k0 += BKF) {
#pragma unroll
        for (int i = 0; i < 4; ++i) { async_cp16(ag[i], al[i]); ag[i] += BKF * 4; }
#pragma unroll
        for (int i = 0; i < 4; ++i) { async_cp16(bg[i], bl[i]); bg[i] += BKF * 4; }
        __builtin_amdgcn_s_waitcnt(0);
        __syncthreads();

        short8 af[4], bf[4];
#pragma unroll
        for (int im = 0; im < 4; ++im) {
            f32x4 x0 = *(const f32x4*)(As_b + aoff[im][0]);
            f32x4 x1 = *(const f32x4*)(As_b + aoff[im][1]);
            af[im] = pack8_bf16(x0, x1);
        }
#pragma unroll
        for (int jn = 0; jn < 4; ++jn) {
            f32x4 x0 = *(const f32x4*)(Bs_b + boff[jn][0]);
            f32x4 x1 = *(const f32x4*)(Bs_b + boff[jn][1]);
            bf[jn] = pack8_bf16(x0, x1);
        }
#pragma unroll
        for (int im = 0; im < 4; ++im)
#pragma unroll
            for (int jn = 0; jn < 4; ++jn)
                acc[im][jn] = __builtin_amdgcn_mfma_f32_16x16x32_bf16(
                    af[im], bf[jn], acc[im][jn], 0, 0, 0);
        __syncthreads();
    }

#pragma unroll
    for (int im = 0; im < 4; ++im) {
#pragma unroll
        for (int reg = 0; reg < 4; ++reg) {
            int r = wm + im * 16 + quad * 4 + reg;
            if (r < vcnt) {
                float* orow = out + (size_t)toks[r] * OUT_FEAT + (n0 + wn + lcol);
#pragma unroll
                for (int jn = 0; jn < 4; ++jn)
                    orow[jn * 16] = acc[im][jn][reg];
            }
        }
    }
}

extern "C" void kernel_launch(void* const* d_in, const int* in_sizes, int n_in,
                              void* d_out, int out_size, void* d_ws, size_t ws_size,
                              hipStream_t stream) {
    const float* inp    = (const float*)d_in[0];   // fp32 [4096,1024]
    const int*   gate   = (const int*)d_in[1];     // int32 [4096]
    const float* weight = (const float*)d_in[2];   // fp32 [8,4096,1024]
    float*       out    = (float*)d_out;           // fp32 [4096,4096]
    (void)in_sizes; (void)n_in; (void)out_size;

    const size_t n_inp = (size_t)N_TOKENS * IN_FEAT;                 // 4M
    const size_t n_w   = (size_t)NUM_EXPERT * OUT_FEAT * IN_FEAT;    // 32M
    const size_t ws_need = (n_inp + n_w) * 2;                        // 72 MB

    dim3 grid(OUT_FEAT / BN, MAX_ROW_TILES);
    if (ws_size >= ws_need) {
        unsigned short* wsA = (unsigned short*)d_ws;
        unsigned short* wsB = wsA + n_inp;
        cvt_bf16<<<512,  256, 0, stream>>>((const float4*)inp,    (uint2*)wsA, (int)(n_inp / 4));
        cvt_bf16<<<2048, 256, 0, stream>>>((const float4*)weight, (uint2*)wsB, (int)(n_w / 4));
        moe_gemm_bf16<<<grid, 256, 0, stream>>>(wsA, wsB, gate, out);
    } else {
        moe_gemm_f32<<<grid, 256, 0, stream>>>(inp, weight, gate, out);
    }
}